// Round 1
// baseline (342.754 us; speedup 1.0000x reference)
//
#include <hip/hip_runtime.h>

// Window attention, b=8 s=4094 nh=8 h=64, window 127 (radius 63), f32 I/O.
// Semantics (from reference): query p attends keys g in [p-63, p+63];
// out-of-range g contributes score 0 (zero-padded K) and value 0 (zero-padded V)
// to the softmax. Layouts: q/k/v/out all (b, s, nh, h) row-major.
//
// Structure: 1 wave (64 thr) per 32 queries per (b,n). bf16 MFMA 16x16x32.
//   A/B frag: lane l holds X[row = l&15][k = (l>>4)*8 + j], j=0..7 (guide §3)
//   C/D frag: lane l, reg r holds D[row = (l>>4)*4 + r][col = l&15]  (m89)
// P (softmax probs) round-trips through a 6 KiB swizzled LDS tile
// ([16 rows][192 cols] bf16, row stride 384B = 3*128B so the
// byte ^= (row&7)<<4 XOR swizzle stays bijective within the row).

#define S_LEN 4094
#define NHEAD 8
#define HDIM  64
#define ROWSTR (NHEAD * HDIM)   // 512 floats per sequence position

typedef float f32x4 __attribute__((ext_vector_type(4)));
typedef short s16x8 __attribute__((ext_vector_type(8)));
typedef int   i32x4 __attribute__((ext_vector_type(4)));

static __device__ __forceinline__ short f2bf(float f) {
    union { float f; unsigned u; } a; a.f = f;
    unsigned u = a.u + 0x7FFFu + ((a.u >> 16) & 1u);   // RNE
    return (short)(u >> 16);
}

static __device__ __forceinline__ s16x8 pack8(f32x4 x0, f32x4 x1) {
    s16x8 r;
    r[0] = f2bf(x0[0]); r[1] = f2bf(x0[1]); r[2] = f2bf(x0[2]); r[3] = f2bf(x0[3]);
    r[4] = f2bf(x1[0]); r[5] = f2bf(x1[1]); r[6] = f2bf(x1[2]); r[7] = f2bf(x1[3]);
    return r;
}

__global__ __launch_bounds__(64)
void win_attn(const float* __restrict__ q, const float* __restrict__ k,
              const float* __restrict__ v, float* __restrict__ out)
{
    __shared__ __align__(16) short Pb[16 * 192];   // 6 KiB

    const int lane = threadIdx.x;
    const int u    = lane >> 4;     // quarter 0..3
    const int c16  = lane & 15;

    const int q0 = blockIdx.x * 32;                       // first query of chunk
    const int bn = (int)blockIdx.z * (S_LEN * ROWSTR) + (int)blockIdx.y * HDIM;

    for (int rb = 0; rb < 2; ++rb) {
        const int qbase = q0 + rb * 16;

        // ---- Q fragments (h dim split into two K=32 halves), scaled by 1/8 ----
        s16x8 aq[2];
        {
            int qr = qbase + c16; if (qr > S_LEN - 1) qr = S_LEN - 1;  // clamp tail
            const float* qp = q + bn + qr * ROWSTR + u * 8;
            #pragma unroll
            for (int hf = 0; hf < 2; ++hf) {
                f32x4 x0 = *(const f32x4*)(qp + hf * 32);
                f32x4 x1 = *(const f32x4*)(qp + hf * 32 + 4);
                x0 *= 0.125f; x1 *= 0.125f;
                aq[hf] = pack8(x0, x1);
            }
        }

        // ---- QK^T: 9 key tiles of 16 (band for 16 rows spans 142 keys) ----
        // local coords: t = key slot in [0,160), key g = q0 - 63 + t
        f32x4 sc[9];
        #pragma unroll
        for (int j = 0; j < 9; ++j) {
            const int tb = (rb + j) * 16;
            const int g  = q0 - 63 + tb + c16;
            const bool ok = (g >= 0) && (g < S_LEN);
            int gc = g; if (gc < 0) gc = 0; if (gc > S_LEN - 1) gc = S_LEN - 1;
            const float* kp = k + bn + gc * ROWSTR + u * 8;
            const float zf = ok ? 1.f : 0.f;   // zero-pad OOR keys -> score 0
            f32x4 acc = {0.f, 0.f, 0.f, 0.f};
            #pragma unroll
            for (int hf = 0; hf < 2; ++hf) {
                f32x4 x0 = *(const f32x4*)(kp + hf * 32);
                f32x4 x1 = *(const f32x4*)(kp + hf * 32 + 4);
                x0 *= zf; x1 *= zf;
                acc = __builtin_amdgcn_mfma_f32_16x16x32_bf16(aq[hf], pack8(x0, x1), acc, 0, 0, 0);
            }
            sc[j] = acc;
        }

        // ---- band mask + softmax (rows i = rb*16 + u*4 + r, cols t) ----
        const int i0 = rb * 16 + u * 4;
        float m[4];
        #pragma unroll
        for (int r = 0; r < 4; ++r) m[r] = -__builtin_inff();
        #pragma unroll
        for (int j = 0; j < 9; ++j) {
            const int t = (rb + j) * 16 + c16;
            #pragma unroll
            for (int r = 0; r < 4; ++r) {
                const int i = i0 + r;
                const bool inb = (t >= i) && (t <= i + 126);
                float val = inb ? sc[j][r] : -__builtin_inff();
                sc[j][r] = val;
                m[r] = fmaxf(m[r], val);
            }
        }
        #pragma unroll
        for (int msk = 1; msk <= 8; msk <<= 1) {
            #pragma unroll
            for (int r = 0; r < 4; ++r)
                m[r] = fmaxf(m[r], __shfl_xor(m[r], msk, 64));
        }
        float d[4] = {0.f, 0.f, 0.f, 0.f};
        #pragma unroll
        for (int j = 0; j < 9; ++j) {
            #pragma unroll
            for (int r = 0; r < 4; ++r) {
                float p = __expf(sc[j][r] - m[r]);   // exp(-inf - m) = 0
                sc[j][r] = p;
                d[r] += p;
            }
        }
        #pragma unroll
        for (int msk = 1; msk <= 8; msk <<= 1) {
            #pragma unroll
            for (int r = 0; r < 4; ++r)
                d[r] += __shfl_xor(d[r], msk, 64);
        }
        float rd[4];
        #pragma unroll
        for (int r = 0; r < 4; ++r) rd[r] = 1.f / d[r];

        // ---- P -> LDS (bf16, swizzled). Zero-fill first: unwritten slots must
        //      be 0 (PV kf blocks over-cover the band). Single wave: program
        //      order gives LDS write->read ordering, no barrier needed. ----
        {
            const i32x4 zz = {0, 0, 0, 0};
            #pragma unroll
            for (int z = 0; z < 6; ++z)
                ((i32x4*)Pb)[z * 64 + lane] = zz;
        }
        #pragma unroll
        for (int j = 0; j < 9; ++j) {
            const int t = (rb + j) * 16 + c16;
            #pragma unroll
            for (int r = 0; r < 4; ++r) {
                const int ir = u * 4 + r;            // P row (query within rb)
                int off = ir * 384 + t * 2;
                off ^= (ir & 7) << 4;
                *(short*)((char*)Pb + off) = f2bf(sc[j][r]);
            }
        }

        // ---- PV: A = P (from LDS), B = V (gathered from global, zero-pad) ----
        s16x8 pa[5];
        #pragma unroll
        for (int kf = 0; kf < 5; ++kf) {
            int aoff = c16 * 384 + kf * 64 + u * 16;
            aoff ^= (c16 & 7) << 4;
            pa[kf] = *(const s16x8*)((const char*)Pb + aoff);
        }
        #pragma unroll
        for (int ht = 0; ht < 4; ++ht) {
            f32x4 o = {0.f, 0.f, 0.f, 0.f};
            #pragma unroll
            for (int kf = 0; kf < 5; ++kf) {
                s16x8 bv;
                #pragma unroll
                for (int jj = 0; jj < 8; ++jj) {
                    const int g = q0 - 63 + kf * 32 + u * 8 + jj;
                    float x = (g >= 0 && g < S_LEN)
                              ? v[bn + g * ROWSTR + ht * 16 + c16] : 0.f;
                    bv[jj] = f2bf(x);
                }
                o = __builtin_amdgcn_mfma_f32_16x16x32_bf16(pa[kf], bv, o, 0, 0, 0);
            }
            #pragma unroll
            for (int r = 0; r < 4; ++r) {
                const int p = qbase + u * 4 + r;
                if (p < S_LEN)
                    out[bn + p * ROWSTR + ht * 16 + c16] = o[r] * rd[r];
            }
        }
    }
}

extern "C" void kernel_launch(void* const* d_in, const int* in_sizes, int n_in,
                              void* d_out, int out_size, void* d_ws, size_t ws_size,
                              hipStream_t stream) {
    const float* q = (const float*)d_in[0];
    const float* k = (const float*)d_in[1];
    const float* v = (const float*)d_in[2];
    float* o = (float*)d_out;
    const int B = in_sizes[0] / (S_LEN * NHEAD * HDIM);
    dim3 grid((S_LEN + 31) / 32, NHEAD, B);   // 128 x 8 x 8 = 8192 waves
    win_attn<<<grid, dim3(64), 0, stream>>>(q, k, v, o);
}

// Round 2
// 76.034 us; speedup vs baseline: 4.5079x; 4.5079x over previous
//
#include <hip/hip_runtime.h>

// Window attention, b=8 s=4094 nh=8 h=64, radius 63, f32 I/O.
// Round 2: 256-thr blocks (4 waves) / 128 queries; K + V^T staged bf16 in
// 64 KiB swizzled LDS; swapped QK^T (S^T = K·Q^T) keeps each query's row
// lane-local for softmax; P redistributed to PV A-frags via cvt_pk + shfl
// (no P-LDS buffer -> 2 blocks/CU).
//
// MFMA 16x16x32 bf16 layouts (verified by round-1 pass):
//   A: lane l holds A[row=l&15][k=(l>>4)*8+j]   B: B[k=(l>>4)*8+j][col=l&15]
//   D: lane l reg r holds D[row=(l>>4)*4+r][col=l&15]

#define S_LEN 4094
#define NHEAD 8
#define HDIM  64
#define ROWSTR 512

typedef float f32x4 __attribute__((ext_vector_type(4)));
typedef short s16x8 __attribute__((ext_vector_type(8)));
typedef int   i32x2 __attribute__((ext_vector_type(2)));
typedef int   i32x4 __attribute__((ext_vector_type(4)));

static __device__ __forceinline__ unsigned cvt_pk(float lo, float hi) {
    unsigned r;
    asm("v_cvt_pk_bf16_f32 %0, %1, %2" : "=v"(r) : "v"(lo), "v"(hi));
    return r;
}

// K tile: [256 keys][64 h] bf16, row 128 B, swizzle ^((key&7)<<4)
static __device__ __forceinline__ int koff(int kr, int h) {
    return ((kr << 7) + (h << 1)) ^ ((kr & 7) << 4);
}
// V^T tile: [64 h][256 keys] bf16, row 512 B, swizzle ^((h&7)<<4)
static __device__ __forceinline__ int voff(int h, int kc) {
    return ((h << 9) + (kc << 1)) ^ ((h & 7) << 4);
}

__global__ __launch_bounds__(256, 2)
void win_attn(const float* __restrict__ q, const float* __restrict__ k,
              const float* __restrict__ v, float* __restrict__ out)
{
    __shared__ __align__(16) short Klds[256 * 64];   // 32 KiB
    __shared__ __align__(16) short Vtld[64 * 256];   // 32 KiB

    const int tid  = threadIdx.x;
    const int lane = tid & 63;
    const int w    = tid >> 6;
    const int u    = lane >> 4;
    const int c16  = lane & 15;

    const int q0 = blockIdx.x * 128;
    const int g0 = q0 - 63;                      // key of LDS row 0
    const size_t bn = (size_t)blockIdx.z * (S_LEN * ROWSTR) + (size_t)blockIdx.y * HDIM;
    const float* kg = k + bn;
    const float* vg = v + bn;

    // ---- stage K: thread reads f32x4, packs, ds_write_b64 ----
    #pragma unroll
    for (int p = 0; p < 16; ++p) {
        int e  = p * 1024 + tid * 4;
        int kr = e >> 6, h4 = e & 63;
        int g  = g0 + kr;
        f32x4 x = {0.f, 0.f, 0.f, 0.f};
        if (g >= 0 && g < S_LEN) x = *(const f32x4*)(kg + (size_t)g * ROWSTR + h4);
        i32x2 wd; wd[0] = (int)cvt_pk(x[0], x[1]); wd[1] = (int)cvt_pk(x[2], x[3]);
        *(i32x2*)((char*)Klds + koff(kr, h4)) = wd;
    }
    // ---- stage V^T: read 2 key-rows' h-quad, pack key-pairs, ds_write_b32 ----
    #pragma unroll
    for (int p = 0; p < 8; ++p) {
        int unit = p * 256 + tid;
        int pr = unit >> 4, hq = unit & 15;
        int g  = g0 + pr * 2;
        f32x4 x0 = {0.f,0.f,0.f,0.f}, x1 = {0.f,0.f,0.f,0.f};
        if (g >= 0 && g < S_LEN)             x0 = *(const f32x4*)(vg + (size_t)g * ROWSTR + hq * 4);
        if (g + 1 >= 0 && g + 1 < S_LEN)     x1 = *(const f32x4*)(vg + (size_t)(g + 1) * ROWSTR + hq * 4);
        #pragma unroll
        for (int i = 0; i < 4; ++i) {
            unsigned wd = cvt_pk(x0[i], x1[i]);   // V[g][h], V[g+1][h]
            *(unsigned*)((char*)Vtld + voff(hq * 4 + i, pr * 2)) = wd;
        }
    }
    __syncthreads();

    const int qw = q0 + w * 32;
    const int sA = ((u & 1) * 2) * 16 + c16;   // source lane for frag lo half
    const int sB = sA + 16;                    // and hi half
    const bool hiHalf = (u >> 1) != 0;

    #pragma unroll
    for (int rb = 0; rb < 2; ++rb) {
        const int qbase = qw + rb * 16;

        // ---- Q fragments (B operand), scaled by h^-0.5 = 1/8 ----
        s16x8 bq[2];
        {
            int qr = qbase + c16; if (qr > S_LEN - 1) qr = S_LEN - 1;
            const float* qp = q + bn + (size_t)qr * ROWSTR + u * 8;
            #pragma unroll
            for (int hf = 0; hf < 2; ++hf) {
                f32x4 x0 = *(const f32x4*)(qp + hf * 32);
                f32x4 x1 = *(const f32x4*)(qp + hf * 32 + 4);
                x0 *= 0.125f; x1 *= 0.125f;
                i32x4 wd;
                wd[0] = (int)cvt_pk(x0[0], x0[1]); wd[1] = (int)cvt_pk(x0[2], x0[3]);
                wd[2] = (int)cvt_pk(x1[0], x1[1]); wd[3] = (int)cvt_pk(x1[2], x1[3]);
                bq[hf] = __builtin_bit_cast(s16x8, wd);
            }
        }

        // ---- S^T = K·Q^T : lane holds S[q=c16][key=(rb+j)*16 + u*4+r] ----
        f32x4 sc[9];
        #pragma unroll
        for (int j = 0; j < 9; ++j) {
            int krow = w * 32 + (rb + j) * 16 + c16;
            s16x8 ka0 = *(const s16x8*)((const char*)Klds + koff(krow, u * 8));
            s16x8 ka1 = *(const s16x8*)((const char*)Klds + koff(krow, 32 + u * 8));
            f32x4 acc = {0.f, 0.f, 0.f, 0.f};
            acc = __builtin_amdgcn_mfma_f32_16x16x32_bf16(ka0, bq[0], acc, 0, 0, 0);
            acc = __builtin_amdgcn_mfma_f32_16x16x32_bf16(ka1, bq[1], acc, 0, 0, 0);
            sc[j] = acc;
        }

        // ---- band mask + softmax (query = c16; reduce over r and u) ----
        const int iq = rb * 16 + c16;
        float m = -__builtin_inff();
        #pragma unroll
        for (int j = 0; j < 9; ++j) {
            #pragma unroll
            for (int r = 0; r < 4; ++r) {
                int t = (rb + j) * 16 + u * 4 + r;
                bool inb = (t >= iq) && (t <= iq + 126);
                float val = inb ? sc[j][r] : -__builtin_inff();
                sc[j][r] = val;
                m = fmaxf(m, val);
            }
        }
        m = fmaxf(m, __shfl_xor(m, 16, 64));
        m = fmaxf(m, __shfl_xor(m, 32, 64));
        float d = 0.f;
        #pragma unroll
        for (int j = 0; j < 9; ++j) {
            #pragma unroll
            for (int r = 0; r < 4; ++r) {
                float pv = __expf(sc[j][r] - m);
                sc[j][r] = pv;
                d += pv;
            }
        }
        d += __shfl_xor(d, 16, 64);
        d += __shfl_xor(d, 32, 64);
        const float rdv = 1.f / d;

        // pack P rows (1/d folded in): w0 = keys r0,r1; w1 = keys r2,r3
        int w0[9], w1[9];
        #pragma unroll
        for (int j = 0; j < 9; ++j) {
            w0[j] = (int)cvt_pk(sc[j][0] * rdv, sc[j][1] * rdv);
            w1[j] = (int)cvt_pk(sc[j][2] * rdv, sc[j][3] * rdv);
        }

        // ---- distribute P^T -> PV A-frags: lane needs P[q=c16][kf*32+u*8+j] ----
        s16x8 pa[5];
        #pragma unroll
        for (int kf = 0; kf < 5; ++kf) {
            const int jtA = 2 * kf - rb;       // tile for dests u<2
            const int jtB = 2 * kf + 1 - rb;   // tile for dests u>=2
            int a0 = 0, a1 = 0, b0 = 0, b1 = 0;
            int e0 = 0, e1 = 0, f0 = 0, f1 = 0;
            if (jtA >= 0 && jtA <= 8) {
                a0 = __shfl(w0[jtA], sA, 64); a1 = __shfl(w1[jtA], sA, 64);
                b0 = __shfl(w0[jtA], sB, 64); b1 = __shfl(w1[jtA], sB, 64);
            }
            if (jtB >= 0 && jtB <= 8) {
                e0 = __shfl(w0[jtB], sA, 64); e1 = __shfl(w1[jtB], sA, 64);
                f0 = __shfl(w0[jtB], sB, 64); f1 = __shfl(w1[jtB], sB, 64);
            }
            i32x4 wd;
            wd[0] = hiHalf ? e0 : a0;
            wd[1] = hiHalf ? e1 : a1;
            wd[2] = hiHalf ? f0 : b0;
            wd[3] = hiHalf ? f1 : b1;
            pa[kf] = __builtin_bit_cast(s16x8, wd);
        }

        // ---- PV: B = V^T tile reads (contiguous in key) ----
        #pragma unroll
        for (int ht = 0; ht < 4; ++ht) {
            f32x4 o = {0.f, 0.f, 0.f, 0.f};
            #pragma unroll
            for (int kf = 0; kf < 5; ++kf) {
                s16x8 bv = *(const s16x8*)((const char*)Vtld +
                             voff(ht * 16 + c16, w * 32 + kf * 32 + u * 8));
                o = __builtin_amdgcn_mfma_f32_16x16x32_bf16(pa[kf], bv, o, 0, 0, 0);
            }
            #pragma unroll
            for (int r = 0; r < 4; ++r) {
                int p = qbase + u * 4 + r;
                if (p < S_LEN)
                    out[bn + (size_t)p * ROWSTR + ht * 16 + c16] = o[r];
            }
        }
    }
}

extern "C" void kernel_launch(void* const* d_in, const int* in_sizes, int n_in,
                              void* d_out, int out_size, void* d_ws, size_t ws_size,
                              hipStream_t stream) {
    const float* q = (const float*)d_in[0];
    const float* k = (const float*)d_in[1];
    const float* v = (const float*)d_in[2];
    float* o = (float*)d_out;
    const int B = in_sizes[0] / (S_LEN * NHEAD * HDIM);
    dim3 grid((S_LEN + 127) / 128, NHEAD, B);   // 32 x 8 x 8 = 2048 blocks
    win_attn<<<grid, dim3(256), 0, stream>>>(q, k, v, o);
}

// Round 3
// 61.515 us; speedup vs baseline: 5.5719x; 1.2360x over previous
//
#include <hip/hip_runtime.h>

// Window attention, b=8 s=4094 nh=8 h=64, radius 63, f32 I/O.
// Round 3: persistent blocks (512 blocks, 4 q-chunks of 128 each) with a
// rolling 256-key ring in LDS (col = (g+63)&255 keeps 16B reads wrap-free)
// and T14 register prefetch: next chunk's 128 NEW keys (K+V) issued before
// compute of the current chunk, written to LDS after it. Halves staging
// traffic and hides the staging HBM latency for 3 of 4 chunks.
//
// MFMA 16x16x32 bf16 layouts (verified rounds 1-2):
//   A: lane l holds A[row=l&15][k=(l>>4)*8+j]   B: B[k=(l>>4)*8+j][col=l&15]
//   D: lane l reg r holds D[row=(l>>4)*4+r][col=l&15]

#define S_LEN 4094
#define NHEAD 8
#define HDIM  64
#define ROWSTR 512

typedef float f32x4 __attribute__((ext_vector_type(4)));
typedef short s16x8 __attribute__((ext_vector_type(8)));
typedef int   i32x2 __attribute__((ext_vector_type(2)));
typedef int   i32x4 __attribute__((ext_vector_type(4)));

static __device__ __forceinline__ unsigned cvt_pk(float lo, float hi) {
    unsigned r;
    asm("v_cvt_pk_bf16_f32 %0, %1, %2" : "=v"(r) : "v"(lo), "v"(hi));
    return r;
}

// K tile: [256 rows][64 h] bf16, row 128 B, swizzle ^((row&7)<<4)
static __device__ __forceinline__ int koff(int kr, int h) {
    return ((kr << 7) + (h << 1)) ^ ((kr & 7) << 4);
}
// V^T tile: [64 h][256 cols] bf16, row 512 B, swizzle ^((h&7)<<4)
static __device__ __forceinline__ int voff(int h, int kc) {
    return ((h << 9) + (kc << 1)) ^ ((h & 7) << 4);
}

static __device__ __forceinline__ f32x4 gload(const float* p, bool ok) {
    f32x4 x = {0.f, 0.f, 0.f, 0.f};
    if (ok) x = *(const f32x4*)p;
    return x;
}

__global__ __launch_bounds__(256, 2)
void win_attn(const float* __restrict__ q, const float* __restrict__ k,
              const float* __restrict__ v, float* __restrict__ out)
{
    __shared__ __align__(16) short Klds[256 * 64];   // 32 KiB
    __shared__ __align__(16) short Vtld[64 * 256];   // 32 KiB

    const int tid  = threadIdx.x;
    const int lane = tid & 63;
    const int w    = tid >> 6;
    const int u    = lane >> 4;
    const int c16  = lane & 15;

    const int q0b = blockIdx.x * 512;                 // first query of block
    const size_t bn = (size_t)blockIdx.z * (S_LEN * ROWSTR) + (size_t)blockIdx.y * HDIM;
    const float* qg = q + bn;
    const float* kg = k + bn;
    const float* vg = v + bn;

    // ---- prologue: full stage of keys [q0b-65, q0b+190] (256 keys) ----
    #pragma unroll
    for (int p = 0; p < 16; ++p) {
        int e  = p * 1024 + tid * 4;
        int krl = e >> 6, h4 = e & 63;
        int g  = q0b - 65 + krl;
        f32x4 x = gload(kg + (size_t)g * ROWSTR + h4, g >= 0 && g < S_LEN);
        int row = (g + 63) & 255;
        i32x2 wd; wd[0] = (int)cvt_pk(x[0], x[1]); wd[1] = (int)cvt_pk(x[2], x[3]);
        *(i32x2*)((char*)Klds + koff(row, h4)) = wd;
    }
    #pragma unroll
    for (int p = 0; p < 8; ++p) {
        int unit = p * 256 + tid;
        int pr = unit >> 4, hq = unit & 15;
        int g  = q0b - 65 + pr * 2;
        f32x4 x0 = gload(vg + (size_t)g * ROWSTR + hq * 4, g >= 0 && g < S_LEN);
        f32x4 x1 = gload(vg + (size_t)(g + 1) * ROWSTR + hq * 4, g + 1 >= 0 && g + 1 < S_LEN);
        int c = (g + 63) & 255;
        #pragma unroll
        for (int i = 0; i < 4; ++i)
            *(unsigned*)((char*)Vtld + voff(hq * 4 + i, c)) = cvt_pk(x0[i], x1[i]);
    }
    __syncthreads();

    const int sA = ((u & 1) * 2) * 16 + c16;   // shuffle source lanes
    const int sB = sA + 16;
    const bool hiHalf = (u >> 1) != 0;

    f32x4 kpre[8], vp0[4], vp1[4];

    for (int t = 0; t < 4; ++t) {
        const int qt  = q0b + (t << 7);
        const int qtm = qt & 255;

        // ---- Q loads for this chunk (latency hidden under prefetch issue) ----
        f32x4 qld[2][4];
        #pragma unroll
        for (int rb = 0; rb < 2; ++rb) {
            int qr = qt + w * 32 + rb * 16 + c16;
            if (qr > S_LEN - 1) qr = S_LEN - 1;
            const float* qp = qg + (size_t)qr * ROWSTR + u * 8;
            qld[rb][0] = *(const f32x4*)(qp);
            qld[rb][1] = *(const f32x4*)(qp + 4);
            qld[rb][2] = *(const f32x4*)(qp + 32);
            qld[rb][3] = *(const f32x4*)(qp + 36);
        }

        // ---- prefetch next chunk's 128 NEW keys [qt+191, qt+318] -> regs ----
        if (t < 3) {
            #pragma unroll
            for (int p = 0; p < 8; ++p) {
                int e  = p * 1024 + tid * 4;
                int krl = e >> 6, h4 = e & 63;
                int g  = qt + 191 + krl;
                kpre[p] = gload(kg + (size_t)g * ROWSTR + h4, g < S_LEN);
            }
            #pragma unroll
            for (int p = 0; p < 4; ++p) {
                int unit = p * 256 + tid;
                int pr = unit >> 4, hq = unit & 15;
                int g  = qt + 191 + pr * 2;
                vp0[p] = gload(vg + (size_t)g * ROWSTR + hq * 4, g < S_LEN);
                vp1[p] = gload(vg + (size_t)(g + 1) * ROWSTR + hq * 4, g + 1 < S_LEN);
            }
        }
        __builtin_amdgcn_sched_barrier(0);

        // ================= compute chunk t =================
        #pragma unroll
        for (int rb = 0; rb < 2; ++rb) {
            // Q fragments (B operand), scaled by h^-0.5 = 1/8
            s16x8 bq[2];
            #pragma unroll
            for (int hf = 0; hf < 2; ++hf) {
                f32x4 x0 = qld[rb][hf * 2]     * 0.125f;
                f32x4 x1 = qld[rb][hf * 2 + 1] * 0.125f;
                i32x4 wd;
                wd[0] = (int)cvt_pk(x0[0], x0[1]); wd[1] = (int)cvt_pk(x0[2], x0[3]);
                wd[2] = (int)cvt_pk(x1[0], x1[1]); wd[3] = (int)cvt_pk(x1[2], x1[3]);
                bq[hf] = __builtin_bit_cast(s16x8, wd);
            }

            // S^T = K·Q^T : lane holds S[q=c16][key=(rb+j)*16 + u*4+r]
            f32x4 sc[9];
            #pragma unroll
            for (int j = 0; j < 9; ++j) {
                int krow = (qtm + w * 32 + (rb + j) * 16 + c16) & 255;
                s16x8 ka0 = *(const s16x8*)((const char*)Klds + koff(krow, u * 8));
                s16x8 ka1 = *(const s16x8*)((const char*)Klds + koff(krow, 32 + u * 8));
                f32x4 acc = {0.f, 0.f, 0.f, 0.f};
                acc = __builtin_amdgcn_mfma_f32_16x16x32_bf16(ka0, bq[0], acc, 0, 0, 0);
                acc = __builtin_amdgcn_mfma_f32_16x16x32_bf16(ka1, bq[1], acc, 0, 0, 0);
                sc[j] = acc;
            }

            // band mask (only tiles j=0,7,8 can violate the band) + softmax
            const int iq = rb * 16 + c16;
            float m = -__builtin_inff();
            #pragma unroll
            for (int j = 0; j < 9; ++j) {
                #pragma unroll
                for (int r = 0; r < 4; ++r) {
                    if (j == 0 || j >= 7) {
                        int tl = (rb + j) * 16 + u * 4 + r;
                        bool inb = (tl >= iq) && (tl <= iq + 126);
                        sc[j][r] = inb ? sc[j][r] : -__builtin_inff();
                    }
                    m = fmaxf(m, sc[j][r]);
                }
            }
            m = fmaxf(m, __shfl_xor(m, 16, 64));
            m = fmaxf(m, __shfl_xor(m, 32, 64));
            float d = 0.f;
            #pragma unroll
            for (int j = 0; j < 9; ++j) {
                #pragma unroll
                for (int r = 0; r < 4; ++r) {
                    float pv = __expf(sc[j][r] - m);
                    sc[j][r] = pv;
                    d += pv;
                }
            }
            d += __shfl_xor(d, 16, 64);
            d += __shfl_xor(d, 32, 64);
            const float rdv = 1.f / d;

            // pack P rows (1/d folded in): w0 = keys r0,r1; w1 = keys r2,r3
            int w0[9], w1[9];
            #pragma unroll
            for (int j = 0; j < 9; ++j) {
                w0[j] = (int)cvt_pk(sc[j][0] * rdv, sc[j][1] * rdv);
                w1[j] = (int)cvt_pk(sc[j][2] * rdv, sc[j][3] * rdv);
            }

            // distribute P^T -> PV A-frags: lane needs P[q=c16][kf*32+u*8+j]
            s16x8 pa[5];
            #pragma unroll
            for (int kf = 0; kf < 5; ++kf) {
                const int jtA = 2 * kf - rb;
                const int jtB = 2 * kf + 1 - rb;
                int a0 = 0, a1 = 0, b0 = 0, b1 = 0;
                int e0 = 0, e1 = 0, f0 = 0, f1 = 0;
                if (jtA >= 0 && jtA <= 8) {
                    a0 = __shfl(w0[jtA], sA, 64); a1 = __shfl(w1[jtA], sA, 64);
                    b0 = __shfl(w0[jtA], sB, 64); b1 = __shfl(w1[jtA], sB, 64);
                }
                if (jtB >= 0 && jtB <= 8) {
                    e0 = __shfl(w0[jtB], sA, 64); e1 = __shfl(w1[jtB], sA, 64);
                    f0 = __shfl(w0[jtB], sB, 64); f1 = __shfl(w1[jtB], sB, 64);
                }
                i32x4 wd;
                wd[0] = hiHalf ? e0 : a0;
                wd[1] = hiHalf ? e1 : a1;
                wd[2] = hiHalf ? f0 : b0;
                wd[3] = hiHalf ? f1 : b1;
                pa[kf] = __builtin_bit_cast(s16x8, wd);
            }

            // PV: B = V^T tile reads (contiguous in key, 8-aligned -> no wrap)
            #pragma unroll
            for (int ht = 0; ht < 4; ++ht) {
                f32x4 o = {0.f, 0.f, 0.f, 0.f};
                #pragma unroll
                for (int kf = 0; kf < 5; ++kf) {
                    int col = (qtm + w * 32 + kf * 32 + u * 8) & 255;
                    s16x8 bv = *(const s16x8*)((const char*)Vtld + voff(ht * 16 + c16, col));
                    o = __builtin_amdgcn_mfma_f32_16x16x32_bf16(pa[kf], bv, o, 0, 0, 0);
                }
                #pragma unroll
                for (int r = 0; r < 4; ++r) {
                    int p = qt + w * 32 + rb * 16 + u * 4 + r;
                    if (p < S_LEN)
                        out[bn + (size_t)p * ROWSTR + ht * 16 + c16] = o[r];
                }
            }
        }

        // ---- write prefetched new keys into the ring (rows no longer needed) ----
        if (t < 3) {
            __syncthreads();   // all waves done reading chunk-t LDS state
            #pragma unroll
            for (int p = 0; p < 8; ++p) {
                int e  = p * 1024 + tid * 4;
                int krl = e >> 6, h4 = e & 63;
                int g  = qt + 191 + krl;
                int row = (g + 63) & 255;
                i32x2 wd; wd[0] = (int)cvt_pk(kpre[p][0], kpre[p][1]);
                          wd[1] = (int)cvt_pk(kpre[p][2], kpre[p][3]);
                *(i32x2*)((char*)Klds + koff(row, h4)) = wd;
            }
            #pragma unroll
            for (int p = 0; p < 4; ++p) {
                int unit = p * 256 + tid;
                int pr = unit >> 4, hq = unit & 15;
                int g  = qt + 191 + pr * 2;
                int c  = (g + 63) & 255;
                #pragma unroll
                for (int i = 0; i < 4; ++i)
                    *(unsigned*)((char*)Vtld + voff(hq * 4 + i, c)) = cvt_pk(vp0[p][i], vp1[p][i]);
            }
            __syncthreads();   // ring ready for chunk t+1
        }
    }
}

extern "C" void kernel_launch(void* const* d_in, const int* in_sizes, int n_in,
                              void* d_out, int out_size, void* d_ws, size_t ws_size,
                              hipStream_t stream) {
    const float* q = (const float*)d_in[0];
    const float* k = (const float*)d_in[1];
    const float* v = (const float*)d_in[2];
    float* o = (float*)d_out;
    const int B = in_sizes[0] / (S_LEN * NHEAD * HDIM);
    dim3 grid(8, NHEAD, B);   // 512 persistent blocks, 4 chunks each
    win_attn<<<grid, dim3(256), 0, stream>>>(q, k, v, o);
}